// Round 2
// baseline (206.840 us; speedup 1.0000x reference)
//
#include <hip/hip_runtime.h>

// YOLO loss, memory-bound streaming reduction.
// ws layout: double acc[64][5] (2560 B) | int flag (at byte 2560)
constexpr int NSLOTS = 64;

// --- Kernel 1: zero accumulators + detect has_object_map encoding -----------
// JAX bool may arrive as raw bool (1B), int32, or float32 depending on the
// harness's dtype canonicalization. Classify by inspecting first 1024 dwords:
//   all in {0,1}            -> int32   (flag=1)
//   all in {0,0x3f800000}   -> float32 (flag=2)
//   else                    -> packed uint8 bools (flag=0)
__global__ void yl_detect_zero(const unsigned int* __restrict__ hmap,
                               double* __restrict__ acc,
                               int* __restrict__ flag) {
    __shared__ int ok[2];
    const int t = threadIdx.x;
    if (t < 2) ok[t] = 1;
    __syncthreads();
    bool vi = true, vf = true;
    for (int i = t; i < 1024; i += 256) {
        const unsigned int d = hmap[i];
        vi = vi && (d == 0u || d == 1u);
        vf = vf && (d == 0u || d == 0x3f800000u);
    }
    if (!vi) atomicAnd(&ok[0], 0);
    if (!vf) atomicAnd(&ok[1], 0);
    for (int i = t; i < NSLOTS * 5; i += 256) acc[i] = 0.0;
    __syncthreads();
    if (t == 0) *flag = ok[0] ? 1 : (ok[1] ? 2 : 0);
}

// --- Kernel 2: per-cell loss terms + hierarchical reduction -----------------
__global__ __launch_bounds__(256) void yl_main(
    const float* __restrict__ pred, const float* __restrict__ tb,
    const float* __restrict__ tc, const void* __restrict__ hmap,
    const int* __restrict__ flag_p, double* __restrict__ acc, int cells)
{
    const int cell = blockIdx.x * 256 + threadIdx.x;
    float obj = 0.f, s_cls = 0.f, s_no = 0.f, s_reg = 0.f, s_conf = 0.f;

    if (cell < cells) {
        const int flag = *flag_p;  // wave-uniform scalar load
        if (flag == 1)      obj = (float)((const int*)hmap)[cell];
        else if (flag == 2) obj = ((const float*)hmap)[cell];
        else                obj = (float)((const unsigned char*)hmap)[cell];

        // pred: 30 floats, base byte offset cell*120 (8-aligned) -> 15x float2
        float p[30];
        const float2* p2 = reinterpret_cast<const float2*>(pred + (size_t)cell * 30);
        #pragma unroll
        for (int i = 0; i < 15; ++i) { const float2 v = p2[i]; p[2*i] = v.x; p[2*i+1] = v.y; }

        const float4 tbv = reinterpret_cast<const float4*>(tb)[cell];

        float tcl[20];
        const float4* t4 = reinterpret_cast<const float4*>(tc + (size_t)cell * 20);
        #pragma unroll
        for (int i = 0; i < 5; ++i) {
            const float4 v = t4[i];
            tcl[4*i] = v.x; tcl[4*i+1] = v.y; tcl[4*i+2] = v.z; tcl[4*i+3] = v.w;
        }

        // class loss term: obj * sum((pred_cls - target_cls)^2)
        float c = 0.f;
        #pragma unroll
        for (int i = 0; i < 20; ++i) { const float d = p[10 + i] - tcl[i]; c += d * d; }
        s_cls = obj * c;

        // no-object term: (1-obj) * (sum b1[0:5]^2 + sum b2[0:5]^2)
        float nn = 0.f;
        #pragma unroll
        for (int i = 0; i < 10; ++i) nn += p[i] * p[i];
        s_no = (1.f - obj) * nn;

        // target box -> xyxy (replicate reference ops: x/14 division)
        const float tx1 = tbv.x / 14.f - 0.5f * tbv.z, ty1 = tbv.y / 14.f - 0.5f * tbv.w;
        const float tx2 = tbv.x / 14.f + 0.5f * tbv.z, ty2 = tbv.y / 14.f + 0.5f * tbv.w;
        const float ta  = (tx2 - tx1) * (ty2 - ty1);

        auto iou_f = [&](float x, float y, float w, float h) -> float {
            const float x1 = x / 14.f - 0.5f * w, y1 = y / 14.f - 0.5f * h;
            const float x2 = x / 14.f + 0.5f * w, y2 = y / 14.f + 0.5f * h;
            const float lw = fmaxf(fminf(x2, tx2) - fmaxf(x1, tx1), 0.f);
            const float lh = fmaxf(fminf(y2, ty2) - fmaxf(y1, ty1), 0.f);
            const float inter = lw * lh;
            const float a = (x2 - x1) * (y2 - y1);
            return inter / (a + ta - inter);
        };
        const float iou1 = iou_f(p[0], p[1], p[2], p[3]);
        const float iou2 = iou_f(p[5], p[6], p[7], p[8]);

        // best box select — component-wise (no runtime-indexed private array)
        const bool take1 = iou1 >= iou2;
        const float bx = take1 ? p[0] : p[5];
        const float by = take1 ? p[1] : p[6];
        const float bw = take1 ? p[2] : p[7];
        const float bh = take1 ? p[3] : p[8];
        const float bc = take1 ? p[4] : p[9];
        const float biou = take1 ? iou1 : iou2;

        const float dx = bx - tbv.x, dy = by - tbv.y;
        const float dw = sqrtf(bw) - sqrtf(tbv.z);
        const float dh = sqrtf(bh) - sqrtf(tbv.w);
        s_reg = obj * (dx * dx + dy * dy + dw * dw + dh * dh);
        const float dc = bc - biou;
        s_conf = obj * dc * dc;
    }

    // block reduction: wave64 shfl -> LDS across 4 waves -> spread atomics
    float vals[5] = {obj, s_cls, s_no, s_reg, s_conf};
    #pragma unroll
    for (int i = 0; i < 5; ++i) {
        float v = vals[i];
        #pragma unroll
        for (int off = 32; off > 0; off >>= 1) v += __shfl_down(v, off);
        vals[i] = v;
    }
    __shared__ float red[4][5];
    const int lane = threadIdx.x & 63, wid = threadIdx.x >> 6;
    if (lane == 0) {
        #pragma unroll
        for (int i = 0; i < 5; ++i) red[wid][i] = vals[i];
    }
    __syncthreads();
    if (threadIdx.x < 5) {
        const float s = red[0][threadIdx.x] + red[1][threadIdx.x]
                      + red[2][threadIdx.x] + red[3][threadIdx.x];
        atomicAdd(&acc[(blockIdx.x & (NSLOTS - 1)) * 5 + threadIdx.x], (double)s);
    }
}

// --- Kernel 3: fold 64 slots, compute the 5 outputs -------------------------
__global__ void yl_finalize(const double* __restrict__ acc, float* __restrict__ out,
                            int cells, int nbatch) {
    const int t = threadIdx.x;  // 64 threads
    double v[5];
    #pragma unroll
    for (int i = 0; i < 5; ++i) v[i] = acc[t * 5 + i];
    #pragma unroll
    for (int i = 0; i < 5; ++i) {
        #pragma unroll
        for (int off = 32; off > 0; off >>= 1) v[i] += __shfl_down(v[i], off);
    }
    if (t == 0) {
        const double n_obj = v[0], n_noobj = (double)cells - v[0];
        const float reg_loss  = (float)(v[3] * 5.0 / n_obj);
        const float conf_loss = (float)(v[4] / n_obj);
        const float no_loss   = (float)(0.5 * v[2] / n_noobj);
        const float cls_loss  = (float)(v[1] / (double)nbatch);
        out[1] = reg_loss;
        out[2] = conf_loss;
        out[3] = no_loss;
        out[4] = cls_loss;
        out[0] = reg_loss + conf_loss + no_loss + cls_loss;  // fp32 add order = reference
    }
}

extern "C" void kernel_launch(void* const* d_in, const int* in_sizes, int n_in,
                              void* d_out, int out_size, void* d_ws, size_t ws_size,
                              hipStream_t stream) {
    const float* pred = (const float*)d_in[0];
    const float* tb   = (const float*)d_in[1];
    const float* tc   = (const float*)d_in[2];
    const void*  hm   = d_in[3];
    const int cells  = in_sizes[3];          // N * S * S
    const int nbatch = cells / 196;          // N (S=14)
    double* acc = (double*)d_ws;
    int* flag   = (int*)((char*)d_ws + NSLOTS * 5 * sizeof(double));

    yl_detect_zero<<<1, 256, 0, stream>>>((const unsigned int*)hm, acc, flag);
    const int blocks = (cells + 255) / 256;
    yl_main<<<blocks, 256, 0, stream>>>(pred, tb, tc, hm, flag, acc, cells);
    yl_finalize<<<1, 64, 0, stream>>>(acc, (float*)d_out, cells, nbatch);
}